// Round 3
// baseline (4750.023 us; speedup 1.0000x reference)
//
#include <hip/hip_runtime.h>
#include <hip/hip_bf16.h>

typedef __attribute__((ext_vector_type(8))) short short8;
typedef float f32x4 __attribute__((ext_vector_type(4)));

#define DIM   512
#define HID   2048
#define NB    512
#define ROWSZ (513*512)
#define NWG   512
#define DT    0.0625f

__device__ __forceinline__ float wave_reduce(float s) {
  for (int off = 32; off > 0; off >>= 1) s += __shfl_xor(s, off, 64);
  return s;
}

// two-level grid barrier: 64 slots x 8 arrivals, wg0 aggregates -> gen
__device__ __forceinline__ void grid_barrier(int* slots, int* gen, int target) {
  __syncthreads();
  int t = threadIdx.x;
  if (blockIdx.x == 0) {
    if (t == 0) {
      __threadfence();
      __hip_atomic_fetch_add(&slots[0], 1, __ATOMIC_RELAXED, __HIP_MEMORY_SCOPE_AGENT);
    }
    if (t < 64) {
      while (__hip_atomic_load(&slots[t], __ATOMIC_RELAXED, __HIP_MEMORY_SCOPE_AGENT) < 8 * target) {}
    }
    __syncthreads();
    if (t == 0) {
      __threadfence();
      __hip_atomic_store(gen, target, __ATOMIC_RELAXED, __HIP_MEMORY_SCOPE_AGENT);
    }
  } else {
    if (t == 0) {
      __threadfence();
      __hip_atomic_fetch_add(&slots[blockIdx.x & 63], 1, __ATOMIC_RELAXED, __HIP_MEMORY_SCOPE_AGENT);
      while (__hip_atomic_load(gen, __ATOMIC_RELAXED, __HIP_MEMORY_SCOPE_AGENT) < target) {
        __builtin_amdgcn_s_sleep(2);
      }
      __threadfence();
    }
  }
  __syncthreads();
}

// one-time: f32 [R][C] -> bf16 [C][R] and f32 [C][R]
__global__ void k_transpose_both(const float* __restrict__ src,
                                 __hip_bfloat16* __restrict__ dstb,
                                 float* __restrict__ dstf, int R, int C) {
  __shared__ float tile[32][33];
  int c0 = blockIdx.x * 32, r0 = blockIdx.y * 32;
  int tx = threadIdx.x & 31, ty = threadIdx.x >> 5;
  for (int i = 0; i < 32; i += 8)
    tile[ty + i][tx] = src[(size_t)(r0 + ty + i) * C + c0 + tx];
  __syncthreads();
  for (int i = 0; i < 32; i += 8) {
    float v = tile[tx][ty + i];
    dstb[(size_t)(c0 + ty + i) * R + r0 + tx] = __float2bfloat16(v);
    dstf[(size_t)(c0 + ty + i) * R + r0 + tx] = v;
  }
}

__global__ __launch_bounds__(256, 2) void k_persist(
    const float* __restrict__ y0, const float* __restrict__ Dy0,
    const __hip_bfloat16* __restrict__ W1t, const __hip_bfloat16* __restrict__ W2t,
    const float* __restrict__ W1tf, const float* __restrict__ W2tf,
    const float* __restrict__ b1, const float* __restrict__ b2,
    float* __restrict__ yt, float* __restrict__ a_s,
    __hip_bfloat16* __restrict__ Vbuf, __hip_bfloat16* __restrict__ tbuf,
    int* __restrict__ slots, int* __restrict__ gen,
    float* __restrict__ out) {
  __shared__ __align__(16) short As[32 * 136];
  __shared__ __align__(16) short Bs[64 * 136];
  __shared__ float paccL[2 * 64 * 4];
  __shared__ float c1L[64], c2L[64];

  const int bid = blockIdx.x, t = threadIdx.x;
  const int w = t >> 6, lane = t & 63, quad = lane >> 4, l16 = lane & 15;

  const int mA = (bid & 15) * 32, nA = (bid >> 4) * 64;   // phase A: 16 x 32 tiles of 32x64
  const int mB = (bid & 15) * 32, nB = (bid >> 4) * 16;   // phase B: 16 x 32 tiles of 32x16
  const int msub = w & 1, kpar = w >> 1;

  // persistent register state
  f32x4 DyR = {0.f, 0.f, 0.f, 0.f};
  f32x4 K1 = DyR, K2 = DyR, K3 = DyR;
  float yR = 0.f, kd1 = 0.f, kd2 = 0.f, kd3 = 0.f;

  const int erow0 = mB + msub * 16 + quad * 4;
  const int ecol  = nB + l16;

  // ---- pre-loop init: state regs, Vbuf, yt, out row 0 ----
  if (kpar == 0) {
    for (int r = 0; r < 4; ++r) {
      float v = Dy0[(size_t)(erow0 + r) * DIM + ecol];
      DyR[r] = v;
      Vbuf[(size_t)(erow0 + r) * DIM + ecol] = __float2bfloat16(v);
      out[DIM + (size_t)(erow0 + r) * DIM + ecol] = v;
    }
  }
  if (w == 0) {
    yR = y0[bid];
    if (lane == 0) { yt[bid] = yR; out[bid] = yR; }
  }
  int barid = 1;
  grid_barrier(slots, gen, barid++);

  for (int ss = 0; ss < 16; ++ss) {
    for (int s = 0; s < 4; ++s) {
      const float cn = (s == 2) ? DT : 0.5f * DT;  // coefficient for next stage's argument
      // ================= PHASE A =================
      // h-part: this wg's 64 n-cols (redundant across the 16 m-tile wgs)
      {
        int colIdx = lane >> 2, dgrp = lane & 3;
        int j = nA + w * 16 + colIdx;
        const float* wrow = &W1tf[(size_t)j * DIM + dgrp * 128];
        const float* yv = &yt[dgrp * 128];
        float s0 = 0.f;
        for (int i = 0; i < 128; i += 4) {
          float4 wv = *(const float4*)&wrow[i];
          float4 yy = *(const float4*)&yv[i];
          s0 += wv.x * yy.x + wv.y * yy.y + wv.z * yy.z + wv.w * yy.w;
        }
        s0 += __shfl_xor(s0, 1, 64);
        s0 += __shfl_xor(s0, 2, 64);
        if (dgrp == 0) {
          float a = tanhf(s0 + b1[j]);
          float ap = 1.f - a * a;
          int cw = w * 16 + colIdx;
          c1L[cw] = ap;
          c2L[cw] = -a * ap;
          if ((bid & 15) == 0) a_s[j] = a;
        }
      }
      // gemm1: g = V @ W1t^T, epilogue applies c1*g + c2*g^2 -> tbuf bf16
      {
        const short* Ag = (const short*)Vbuf;
        const short* Bg = (const short*)W1t;
        int rA = t >> 3, cA = (t & 7) * 16;
        int rB = t >> 2, cB = (t & 3) * 32;
        const int wm = (w & 1) * 16, wn = (w >> 1) * 32;
        f32x4 acc0 = {0.f, 0.f, 0.f, 0.f}, acc1 = acc0;
        size_t aoff = (size_t)(mA + rA) * DIM + cA;
        size_t boff = (size_t)(nA + rB) * DIM + cB;
        uint4 ra0 = *(const uint4*)&Ag[aoff], ra1 = *(const uint4*)&Ag[aoff + 8];
        uint4 rb0 = *(const uint4*)&Bg[boff], rb1 = *(const uint4*)&Bg[boff + 8];
        uint4 rb2 = *(const uint4*)&Bg[boff + 16], rb3 = *(const uint4*)&Bg[boff + 24];
        for (int c = 0; c < 4; ++c) {
          __syncthreads();
          *(uint4*)&As[rA * 136 + cA] = ra0; *(uint4*)&As[rA * 136 + cA + 8] = ra1;
          *(uint4*)&Bs[rB * 136 + cB] = rb0; *(uint4*)&Bs[rB * 136 + cB + 8] = rb1;
          *(uint4*)&Bs[rB * 136 + cB + 16] = rb2; *(uint4*)&Bs[rB * 136 + cB + 24] = rb3;
          __syncthreads();
          if (c < 3) {
            size_t ao = aoff + (size_t)(c + 1) * 128, bo = boff + (size_t)(c + 1) * 128;
            ra0 = *(const uint4*)&Ag[ao]; ra1 = *(const uint4*)&Ag[ao + 8];
            rb0 = *(const uint4*)&Bg[bo]; rb1 = *(const uint4*)&Bg[bo + 8];
            rb2 = *(const uint4*)&Bg[bo + 16]; rb3 = *(const uint4*)&Bg[bo + 24];
          }
          for (int kk = 0; kk < 128; kk += 32) {
            short8 a   = *(const short8*)&As[(wm + l16) * 136 + kk + quad * 8];
            short8 b0  = *(const short8*)&Bs[(wn + l16) * 136 + kk + quad * 8];
            short8 b1v = *(const short8*)&Bs[(wn + 16 + l16) * 136 + kk + quad * 8];
            acc0 = __builtin_amdgcn_mfma_f32_16x16x32_bf16(a, b0, acc0, 0, 0, 0);
            acc1 = __builtin_amdgcn_mfma_f32_16x16x32_bf16(a, b1v, acc1, 0, 0, 0);
          }
        }
        int row0 = mA + wm + quad * 4;
        int c0i = wn + l16, c1i = wn + 16 + l16;
        float C1a = c1L[c0i], C2a = c2L[c0i], C1b = c1L[c1i], C2b = c2L[c1i];
        for (int r = 0; r < 4; ++r) {
          float g0 = acc0[r], g1 = acc1[r];
          tbuf[(size_t)(row0 + r) * HID + nA + c0i] = __float2bfloat16(g0 * (C1a + C2a * g0));
          tbuf[(size_t)(row0 + r) * HID + nA + c1i] = __float2bfloat16(g1 * (C1b + C2b * g1));
        }
      }
      grid_barrier(slots, gen, barid++);
      // ================= PHASE B =================
      {
        const short* Ag = (const short*)tbuf;
        const short* Bg = (const short*)W2t;
        int rA = t >> 3, cA = (t & 7) * 16;
        int rB = t >> 4, cB = (t & 15) * 8;
        f32x4 acc = {0.f, 0.f, 0.f, 0.f};
        size_t aoff = (size_t)(mB + rA) * HID + cA;
        size_t boff = (size_t)(nB + rB) * HID + cB;
        uint4 ra0 = *(const uint4*)&Ag[aoff], ra1 = *(const uint4*)&Ag[aoff + 8];
        uint4 rb0 = *(const uint4*)&Bg[boff];
        for (int c = 0; c < 16; ++c) {
          __syncthreads();
          *(uint4*)&As[rA * 136 + cA] = ra0; *(uint4*)&As[rA * 136 + cA + 8] = ra1;
          *(uint4*)&Bs[rB * 136 + cB] = rb0;
          __syncthreads();
          if (c < 15) {
            ra0 = *(const uint4*)&Ag[aoff + (size_t)(c + 1) * 128];
            ra1 = *(const uint4*)&Ag[aoff + (size_t)(c + 1) * 128 + 8];
            rb0 = *(const uint4*)&Bg[boff + (size_t)(c + 1) * 128];
          }
          if ((c & 1) == kpar) {
            for (int kk = 0; kk < 128; kk += 32) {
              short8 a = *(const short8*)&As[(msub * 16 + l16) * 136 + kk + quad * 8];
              short8 b = *(const short8*)&Bs[l16 * 136 + kk + quad * 8];
              acc = __builtin_amdgcn_mfma_f32_16x16x32_bf16(a, b, acc, 0, 0, 0);
            }
          }
        }
        if (kpar == 1) {
          for (int r = 0; r < 4; ++r) paccL[(msub * 64 + lane) * 4 + r] = acc[r];
        }
        __syncthreads();
        if (kpar == 0) {
          f32x4 o = acc;
          for (int r = 0; r < 4; ++r) o[r] += paccL[(msub * 64 + lane) * 4 + r];
          if (s == 0) K1 = o; else if (s == 1) K2 = o; else if (s == 2) K3 = o;
          if (s < 3) {
            for (int r = 0; r < 4; ++r) {
              float v = DyR[r] + cn * o[r];
              Vbuf[(size_t)(erow0 + r) * DIM + ecol] = __float2bfloat16(v);
            }
          } else {
            const float dt6 = DT / 6.f;
            for (int r = 0; r < 4; ++r) {
              float v = DyR[r] + dt6 * (K1[r] + 2.f * K2[r] + 2.f * K3[r] + o[r]);
              DyR[r] = v;
              Vbuf[(size_t)(erow0 + r) * DIM + ecol] = __float2bfloat16(v);
              if (ss & 1) out[(size_t)(ss / 2 + 1) * ROWSZ + DIM + (size_t)(erow0 + r) * DIM + ecol] = v;
            }
          }
        }
      }
      // dy-part: exact f32, one column per wg (wave 0)
      if (w == 0) {
        int j = bid;
        const float* wrow = &W2tf[(size_t)j * HID + lane * 32];
        const float* av = &a_s[lane * 32];
        float s0 = 0.f;
        for (int i = 0; i < 32; i += 4) {
          float4 wv = *(const float4*)&wrow[i];
          float4 aa = *(const float4*)&av[i];
          s0 += wv.x * aa.x + wv.y * aa.y + wv.z * aa.z + wv.w * aa.w;
        }
        s0 = wave_reduce(s0);
        float k4 = s0 + b2[j];
        if (s == 0) kd1 = k4; else if (s == 1) kd2 = k4; else if (s == 2) kd3 = k4;
        if (s < 3) {
          float v = yR + cn * k4;
          if (lane == 0) yt[j] = v;
        } else {
          yR += (DT / 6.f) * (kd1 + 2.f * kd2 + 2.f * kd3 + k4);
          if (lane == 0) {
            yt[j] = yR;
            if (ss & 1) out[(size_t)(ss / 2 + 1) * ROWSZ + j] = yR;
          }
        }
      }
      grid_barrier(slots, gen, barid++);
    }
  }
}

extern "C" void kernel_launch(void* const* d_in, const int* in_sizes, int n_in,
                              void* d_out, int out_size, void* d_ws, size_t ws_size,
                              hipStream_t stream) {
  const float* y0  = (const float*)d_in[1];
  const float* Dy0 = (const float*)d_in[2];
  const float* W1  = (const float*)d_in[3];
  const float* b1  = (const float*)d_in[4];
  const float* W2  = (const float*)d_in[5];
  const float* b2  = (const float*)d_in[6];
  float* out = (float*)d_out;

  char* p = (char*)d_ws;
  auto alloc = [&](size_t bytes) {
    char* r = p;
    p += (bytes + 255) & ~(size_t)255;
    return r;
  };
  __hip_bfloat16* W1t  = (__hip_bfloat16*)alloc((size_t)HID * DIM * 2);
  __hip_bfloat16* W2t  = (__hip_bfloat16*)alloc((size_t)DIM * HID * 2);
  float* W1tf = (float*)alloc((size_t)HID * DIM * 4);
  float* W2tf = (float*)alloc((size_t)DIM * HID * 4);
  __hip_bfloat16* Vbuf = (__hip_bfloat16*)alloc((size_t)NB * DIM * 2);
  __hip_bfloat16* tbuf = (__hip_bfloat16*)alloc((size_t)NB * HID * 2);
  float* yt  = (float*)alloc(DIM * 4);
  float* a_s = (float*)alloc(HID * 4);
  int* slots = (int*)alloc(65 * 4);
  int* gen   = slots + 64;

  hipMemsetAsync(slots, 0, 65 * 4, stream);
  k_transpose_both<<<dim3(HID / 32, DIM / 32), 256, 0, stream>>>(W1, W1t, W1tf, DIM, HID);
  k_transpose_both<<<dim3(DIM / 32, HID / 32), 256, 0, stream>>>(W2, W2t, W2tf, HID, DIM);
  k_persist<<<NWG, 256, 0, stream>>>(y0, Dy0, W1t, W2t, W1tf, W2tf, b1, b2,
                                     yt, a_s, Vbuf, tbuf, slots, gen, out);
}

// Round 5
// 2366.892 us; speedup vs baseline: 2.0069x; 2.0069x over previous
//
#include <hip/hip_runtime.h>
#include <hip/hip_bf16.h>

typedef __attribute__((ext_vector_type(8))) short short8;
typedef float f32x4 __attribute__((ext_vector_type(4)));

#define DIM 512
#define HID 2048
#define NB  512
#define ROWSZ (513*512)
#define DT 0.0625f

__device__ __forceinline__ float bf2f(unsigned short s){ return __uint_as_float(((unsigned)s)<<16); }
__device__ __forceinline__ unsigned short f2bfu(float f){ __hip_bfloat16 h=__float2bfloat16(f); return *(unsigned short*)&h; }

// L1-bypassing (sc0) 8-byte load, compiler-tracked: agent-scope relaxed atomic
__device__ __forceinline__ unsigned long long ald64(const void* p){
  return __hip_atomic_load((const unsigned long long*)p, __ATOMIC_RELAXED, __HIP_MEMORY_SCOPE_AGENT);
}

__device__ __forceinline__ float wave_reduce(float s){
  for (int off=32; off>0; off>>=1) s += __shfl_xor(s, off, 64);
  return s;
}

__device__ __forceinline__ float dot8(uint4 wq, const float* a){
  const unsigned short* ws=(const unsigned short*)&wq;
  float s = 0.f;
  for (int i = 0; i < 8; ++i) s += bf2f(ws[i]) * a[i];
  return s;
}

// XCD-local barrier: 64 wgs, relaxed agent atomics, NO cache fences.
__device__ __forceinline__ void xbar(int* arr, int* gen, int target, int sl){
  asm volatile("s_waitcnt vmcnt(0) lgkmcnt(0)" ::: "memory");
  __syncthreads();
  if (threadIdx.x == 0) {
    __hip_atomic_fetch_add(arr, 1, __ATOMIC_RELAXED, __HIP_MEMORY_SCOPE_AGENT);
    if (sl == 0) {
      while (__hip_atomic_load(arr, __ATOMIC_RELAXED, __HIP_MEMORY_SCOPE_AGENT) < 64*target)
        __builtin_amdgcn_s_sleep(1);
      __hip_atomic_store(gen, target, __ATOMIC_RELAXED, __HIP_MEMORY_SCOPE_AGENT);
    } else {
      while (__hip_atomic_load(gen, __ATOMIC_RELAXED, __HIP_MEMORY_SCOPE_AGENT) < target)
        __builtin_amdgcn_s_sleep(1);
    }
  }
  __syncthreads();
}

__global__ void k_transpose_bf16(const float* __restrict__ src,
                                 __hip_bfloat16* __restrict__ dst, int R, int C) {
  __shared__ float tile[32][33];
  int c0 = blockIdx.x * 32, r0 = blockIdx.y * 32;
  int tx = threadIdx.x & 31, ty = threadIdx.x >> 5;
  for (int i = 0; i < 32; i += 8)
    tile[ty + i][tx] = src[(size_t)(r0 + ty + i) * C + c0 + tx];
  __syncthreads();
  for (int i = 0; i < 32; i += 8)
    dst[(size_t)(c0 + ty + i) * R + r0 + tx] = __float2bfloat16(tile[tx][ty + i]);
}

__global__ __launch_bounds__(256, 2) void k_persist(
    const float* __restrict__ y0, const float* __restrict__ Dy0,
    const unsigned short* __restrict__ W1t, const unsigned short* __restrict__ W2t,
    const float* __restrict__ b1, const float* __restrict__ b2,
    unsigned short* __restrict__ Vbuf, unsigned short* __restrict__ tbuf,
    float* __restrict__ yts, float* __restrict__ a_ss,
    int* __restrict__ ctrl, float* __restrict__ out) {
  __shared__ __align__(16) short As[32 * 136];
  __shared__ __align__(16) short Bs[64 * 136];
  __shared__ float paccL[2 * 64 * 4];
  __shared__ float c1L[64], c2L[64];
  __shared__ float ytL[DIM];
  __shared__ int bcast[2];
  extern __shared__ char dynpad[];  // 24576 B at launch: forces 2 wg/CU

  const int t = threadIdx.x;
  if (t == 0) {
    int x;
    asm volatile("s_getreg_b32 %0, hwreg(HW_REG_XCC_ID)" : "=s"(x));
    x &= 7;
    bcast[0] = x;
    bcast[1] = atomicAdd(&ctrl[x], 1);
  }
  __syncthreads();
  const int xcd = bcast[0];
  const int sl  = bcast[1] & 63;
  int* arr = ctrl + 16 + 32 * xcd;
  int* gen = arr + 16;

  const int w = t >> 6, lane = t & 63, quad = lane >> 4, l16 = lane & 15;
  const int msub = w & 1, kpar = w >> 1;
  const int mA = xcd * 64 + (sl >> 5) * 32, nA = (sl & 31) * 64;
  const int mB = mA, nB = (sl & 31) * 16;
  float* ytx = yts + xcd * DIM;
  float* asx = a_ss + xcd * HID;

  f32x4 DyR = {0.f,0.f,0.f,0.f}, K1 = DyR, K2 = DyR, K3 = DyR;
  float yRc[2] = {0.f,0.f}, kq1[2], kq2[2], kq3[2];
  const int erow0 = mB + msub * 16 + quad * 4;
  const int ecol  = nB + l16;
  const int jy0 = sl * 8 + w * 2;

  // ---- init: register state, Vbuf, yt, out row 0 ----
  if (kpar == 0) {
    for (int r = 0; r < 4; ++r) {
      float v = Dy0[(size_t)(erow0 + r) * DIM + ecol];
      DyR[r] = v;
      Vbuf[(size_t)(erow0 + r) * DIM + ecol] = f2bfu(v);
      out[DIM + (size_t)(erow0 + r) * DIM + ecol] = v;
    }
  }
  for (int cc = 0; cc < 2; ++cc) {
    float v = y0[jy0 + cc];
    yRc[cc] = v;
    if (lane == 0) { ytx[jy0 + cc] = v; if (xcd == 0) out[jy0 + cc] = v; }
  }
  int barid = 1;
  xbar(arr, gen, barid++, sl);

  for (int ss = 0; ss < 16; ++ss) {
    for (int st = 0; st < 4; ++st) {
      const float cn = (st == 2) ? DT : 0.5f * DT;
      // ================= PHASE A =================
      {
        unsigned long long q = ald64(ytx + t * 2);
        ytL[t * 2]     = __uint_as_float((unsigned)q);
        ytL[t * 2 + 1] = __uint_as_float((unsigned)(q >> 32));
      }
      __syncthreads();
      // h-part: this wg's 64 n-cols (x2 redundant per XCD), bf16 weights f32 accum
      {
        int colIdx = lane >> 2, dgrp = lane & 3;
        int j = nA + w * 16 + colIdx;
        const unsigned short* wrow = W1t + (size_t)j * DIM + dgrp * 128;
        const float* yv = ytL + dgrp * 128;
        float s0 = 0.f;
        for (int i = 0; i < 128; i += 8) {
          uint4 wq = *(const uint4*)&wrow[i];
          s0 += dot8(wq, yv + i);
        }
        s0 += __shfl_xor(s0, 1, 64);
        s0 += __shfl_xor(s0, 2, 64);
        if (dgrp == 0) {
          float a = tanhf(s0 + b1[j]);
          float ap = 1.f - a * a;
          c1L[w * 16 + colIdx] = ap;
          c2L[w * 16 + colIdx] = -a * ap;
          asx[j] = a;
        }
      }
      // gemm1: g = V @ W1t^T -> transform -> tbuf
      {
        const int wm = msub * 16, wn = kpar * 32;
        int rA = t >> 3, cA = (t & 7) * 16;
        int rB = t >> 2, cB = (t & 3) * 32;
        f32x4 acc0 = {0.f,0.f,0.f,0.f}, acc1 = acc0;
        size_t aoff = (size_t)(mA + rA) * DIM + cA;
        size_t boff = (size_t)(nA + rB) * DIM + cB;
        unsigned long long qa0 = ald64(Vbuf + aoff), qa1 = ald64(Vbuf + aoff + 4);
        unsigned long long qa2 = ald64(Vbuf + aoff + 8), qa3 = ald64(Vbuf + aoff + 12);
        uint4 rb0 = *(const uint4*)&W1t[boff],      rb1 = *(const uint4*)&W1t[boff + 8];
        uint4 rb2 = *(const uint4*)&W1t[boff + 16], rb3 = *(const uint4*)&W1t[boff + 24];
        for (int c = 0; c < 4; ++c) {
          __syncthreads();
          *(unsigned long long*)&As[rA * 136 + cA]      = qa0;
          *(unsigned long long*)&As[rA * 136 + cA + 4]  = qa1;
          *(unsigned long long*)&As[rA * 136 + cA + 8]  = qa2;
          *(unsigned long long*)&As[rA * 136 + cA + 12] = qa3;
          *(uint4*)&Bs[rB * 136 + cB] = rb0; *(uint4*)&Bs[rB * 136 + cB + 8] = rb1;
          *(uint4*)&Bs[rB * 136 + cB + 16] = rb2; *(uint4*)&Bs[rB * 136 + cB + 24] = rb3;
          if (c < 3) {
            size_t ao = aoff + (size_t)(c + 1) * 128, bo = boff + (size_t)(c + 1) * 128;
            qa0 = ald64(Vbuf + ao); qa1 = ald64(Vbuf + ao + 4);
            qa2 = ald64(Vbuf + ao + 8); qa3 = ald64(Vbuf + ao + 12);
            rb0 = *(const uint4*)&W1t[bo];      rb1 = *(const uint4*)&W1t[bo + 8];
            rb2 = *(const uint4*)&W1t[bo + 16]; rb3 = *(const uint4*)&W1t[bo + 24];
          }
          __syncthreads();
          for (int kk = 0; kk < 128; kk += 32) {
            short8 a   = *(const short8*)&As[(wm + l16) * 136 + kk + quad * 8];
            short8 b0  = *(const short8*)&Bs[(wn + l16) * 136 + kk + quad * 8];
            short8 b1v = *(const short8*)&Bs[(wn + 16 + l16) * 136 + kk + quad * 8];
            acc0 = __builtin_amdgcn_mfma_f32_16x16x32_bf16(a, b0, acc0, 0, 0, 0);
            acc1 = __builtin_amdgcn_mfma_f32_16x16x32_bf16(a, b1v, acc1, 0, 0, 0);
          }
        }
        int row0 = mA + wm + quad * 4;
        int c0i = wn + l16, c1i = wn + 16 + l16;
        float C1a = c1L[c0i], C2a = c2L[c0i], C1b = c1L[c1i], C2b = c2L[c1i];
        for (int r = 0; r < 4; ++r) {
          float g0 = acc0[r], g1 = acc1[r];
          tbuf[(size_t)(row0 + r) * HID + nA + c0i] = f2bfu(g0 * (C1a + C2a * g0));
          tbuf[(size_t)(row0 + r) * HID + nA + c1i] = f2bfu(g1 * (C1b + C2b * g1));
        }
      }
      xbar(arr, gen, barid++, sl);
      // ================= PHASE B =================
      {
        int rA = t >> 3, cA = (t & 7) * 16;
        int rB = t >> 4, cB = (t & 15) * 8;
        f32x4 acc = {0.f,0.f,0.f,0.f};
        size_t aoff = (size_t)(mB + rA) * HID + cA;
        size_t boff = (size_t)(nB + rB) * HID + cB;
        unsigned long long qa0 = ald64(tbuf + aoff), qa1 = ald64(tbuf + aoff + 4);
        unsigned long long qa2 = ald64(tbuf + aoff + 8), qa3 = ald64(tbuf + aoff + 12);
        uint4 rb0 = *(const uint4*)&W2t[boff];
        for (int c = 0; c < 16; ++c) {
          __syncthreads();
          *(unsigned long long*)&As[rA * 136 + cA]      = qa0;
          *(unsigned long long*)&As[rA * 136 + cA + 4]  = qa1;
          *(unsigned long long*)&As[rA * 136 + cA + 8]  = qa2;
          *(unsigned long long*)&As[rA * 136 + cA + 12] = qa3;
          *(uint4*)&Bs[rB * 136 + cB] = rb0;
          if (c < 15) {
            size_t ao = aoff + (size_t)(c + 1) * 128;
            qa0 = ald64(tbuf + ao); qa1 = ald64(tbuf + ao + 4);
            qa2 = ald64(tbuf + ao + 8); qa3 = ald64(tbuf + ao + 12);
            rb0 = *(const uint4*)&W2t[boff + (size_t)(c + 1) * 128];
          }
          __syncthreads();
          if ((c & 1) == kpar) {
            for (int kk = 0; kk < 128; kk += 32) {
              short8 a = *(const short8*)&As[(msub * 16 + l16) * 136 + kk + quad * 8];
              short8 b = *(const short8*)&Bs[l16 * 136 + kk + quad * 8];
              acc = __builtin_amdgcn_mfma_f32_16x16x32_bf16(a, b, acc, 0, 0, 0);
            }
          }
        }
        if (kpar == 1)
          for (int r = 0; r < 4; ++r) paccL[(msub * 64 + lane) * 4 + r] = acc[r];
        __syncthreads();
        if (kpar == 0) {
          f32x4 o = acc;
          for (int r = 0; r < 4; ++r) o[r] += paccL[(msub * 64 + lane) * 4 + r];
          if (st == 0) K1 = o; else if (st == 1) K2 = o; else if (st == 2) K3 = o;
          if (st < 3) {
            for (int r = 0; r < 4; ++r) {
              float v = DyR[r] + cn * o[r];
              Vbuf[(size_t)(erow0 + r) * DIM + ecol] = f2bfu(v);
            }
          } else {
            const float dt6 = DT / 6.f;
            for (int r = 0; r < 4; ++r) {
              float v = DyR[r] + dt6 * (K1[r] + 2.f * K2[r] + 2.f * K3[r] + o[r]);
              DyR[r] = v;
              Vbuf[(size_t)(erow0 + r) * DIM + ecol] = f2bfu(v);
              if (ss & 1) out[(size_t)(ss / 2 + 1) * ROWSZ + DIM + (size_t)(erow0 + r) * DIM + ecol] = v;
            }
          }
        }
      }
      // dy-part: replicated per XCD, bf16 W2t rows, f32 accum
      {
        float aL[32];
        const float* ap = asx + lane * 32;
        for (int i = 0; i < 16; ++i) {
          unsigned long long q = ald64(ap + i * 2);
          aL[2 * i]     = __uint_as_float((unsigned)q);
          aL[2 * i + 1] = __uint_as_float((unsigned)(q >> 32));
        }
        for (int cc = 0; cc < 2; ++cc) {
          int j = jy0 + cc;
          const unsigned short* wrow = W2t + (size_t)j * HID + lane * 32;
          uint4 w0 = *(const uint4*)&wrow[0],  w1 = *(const uint4*)&wrow[8];
          uint4 w2 = *(const uint4*)&wrow[16], w3 = *(const uint4*)&wrow[24];
          float s0 = dot8(w0, aL) + dot8(w1, aL + 8) + dot8(w2, aL + 16) + dot8(w3, aL + 24);
          s0 = wave_reduce(s0);
          float k4 = s0 + b2[j];
          if (st == 0) kq1[cc] = k4; else if (st == 1) kq2[cc] = k4; else if (st == 2) kq3[cc] = k4;
          if (st < 3) {
            if (lane == 0) ytx[j] = yRc[cc] + cn * k4;
          } else {
            yRc[cc] += (DT / 6.f) * (kq1[cc] + 2.f * kq2[cc] + 2.f * kq3[cc] + k4);
            if (lane == 0) {
              ytx[j] = yRc[cc];
              if ((ss & 1) && xcd == 0) out[(size_t)(ss / 2 + 1) * ROWSZ + j] = yRc[cc];
            }
          }
        }
      }
      xbar(arr, gen, barid++, sl);
    }
  }
}

extern "C" void kernel_launch(void* const* d_in, const int* in_sizes, int n_in,
                              void* d_out, int out_size, void* d_ws, size_t ws_size,
                              hipStream_t stream) {
  const float* y0  = (const float*)d_in[1];
  const float* Dy0 = (const float*)d_in[2];
  const float* W1  = (const float*)d_in[3];
  const float* b1  = (const float*)d_in[4];
  const float* W2  = (const float*)d_in[5];
  const float* b2  = (const float*)d_in[6];
  float* out = (float*)d_out;

  char* p = (char*)d_ws;
  auto alloc = [&](size_t bytes) {
    char* r = p;
    p += (bytes + 255) & ~(size_t)255;
    return r;
  };
  unsigned short* W1t  = (unsigned short*)alloc((size_t)HID * DIM * 2);
  unsigned short* W2t  = (unsigned short*)alloc((size_t)DIM * HID * 2);
  unsigned short* Vbuf = (unsigned short*)alloc((size_t)NB * DIM * 2);
  unsigned short* tbuf = (unsigned short*)alloc((size_t)NB * HID * 2);
  float* yts  = (float*)alloc(8 * DIM * 4);
  float* a_ss = (float*)alloc(8 * HID * 4);
  int* ctrl   = (int*)alloc(2048);

  hipMemsetAsync(ctrl, 0, 2048, stream);
  k_transpose_bf16<<<dim3(HID / 32, DIM / 32), 256, 0, stream>>>(W1, (__hip_bfloat16*)W1t, DIM, HID);
  k_transpose_bf16<<<dim3(DIM / 32, HID / 32), 256, 0, stream>>>(W2, (__hip_bfloat16*)W2t, HID, DIM);
  k_persist<<<512, 256, 24576, stream>>>(y0, Dy0, W1t, W2t, b1, b2,
                                         Vbuf, tbuf, yts, a_ss, ctrl, out);
}

// Round 6
// 2328.385 us; speedup vs baseline: 2.0401x; 1.0165x over previous
//
#include <hip/hip_runtime.h>
#include <hip/hip_bf16.h>

typedef __attribute__((ext_vector_type(8))) short short8;
typedef float f32x4 __attribute__((ext_vector_type(4)));
typedef unsigned long long u64;

#define DIM 512
#define HID 2048
#define ROWSZ (513*512)
#define DT 0.0625f

__device__ __forceinline__ float bf2f(unsigned short s){ return __uint_as_float(((unsigned)s)<<16); }
__device__ __forceinline__ unsigned short f2bfu(float f){ __hip_bfloat16 h=__float2bfloat16(f); return *(unsigned short*)&h; }
__device__ __forceinline__ u64 ald64(const void* p){
  return __hip_atomic_load((const u64*)p, __ATOMIC_RELAXED, __HIP_MEMORY_SCOPE_AGENT);
}
__device__ __forceinline__ float dot8(uint4 wq, const float* a){
  const unsigned short* ws=(const unsigned short*)&wq;
  float s=0.f;
#pragma unroll
  for(int i=0;i<8;++i) s += bf2f(ws[i])*a[i];
  return s;
}
// LDS xor swizzle: pitch 128 shorts, 8-short (16B) granules, granule ^= row&7
__device__ __forceinline__ int swz(int row, int col){
  return (row<<7) + (((col>>3) ^ (row&7))<<3) + (col&7);
}

// group barrier: 32 wgs, relaxed agent atomics, no cache maintenance.
__device__ __forceinline__ void xbar(int* arr, int* gen, int target, bool lead){
  asm volatile("s_waitcnt vmcnt(0) lgkmcnt(0)" ::: "memory");
  __syncthreads();
  if (threadIdx.x == 0){
    __hip_atomic_fetch_add(arr, 1, __ATOMIC_RELAXED, __HIP_MEMORY_SCOPE_AGENT);
    if (lead){
      while (__hip_atomic_load(arr, __ATOMIC_RELAXED, __HIP_MEMORY_SCOPE_AGENT) < 32*target)
        __builtin_amdgcn_s_sleep(2);
      __hip_atomic_store(gen, target, __ATOMIC_RELAXED, __HIP_MEMORY_SCOPE_AGENT);
    } else {
      while (__hip_atomic_load(gen, __ATOMIC_RELAXED, __HIP_MEMORY_SCOPE_AGENT) < target)
        __builtin_amdgcn_s_sleep(8);
    }
  }
  __syncthreads();
}

__global__ void k_transpose_bf16(const float* __restrict__ src,
                                 __hip_bfloat16* __restrict__ dst, int R, int C) {
  __shared__ float tile[32][33];
  int c0 = blockIdx.x * 32, r0 = blockIdx.y * 32;
  int tx = threadIdx.x & 31, ty = threadIdx.x >> 5;
  for (int i = 0; i < 32; i += 8)
    tile[ty + i][tx] = src[(size_t)(r0 + ty + i) * C + c0 + tx];
  __syncthreads();
  for (int i = 0; i < 32; i += 8)
    dst[(size_t)(c0 + ty + i) * R + r0 + tx] = __float2bfloat16(tile[tx][ty + i]);
}

__global__ __launch_bounds__(256, 2) void k_persist(
    const float* __restrict__ y0, const float* __restrict__ Dy0,
    const unsigned short* __restrict__ W1t, const unsigned short* __restrict__ W2t,
    const float* __restrict__ b1, const float* __restrict__ b2,
    unsigned short* __restrict__ Vbuf, unsigned short* __restrict__ tbuf,
    float* __restrict__ yts, float* __restrict__ a_ss,
    int* __restrict__ ctrl, float* __restrict__ out) {
  __shared__ __align__(16) short As[2][32 * 128];   // 16 KB
  __shared__ __align__(16) short Bs[2][64 * 128];   // 32 KB
  __shared__ float paccL[512];                      // 2 KB (h-reduce / kpar-reduce)
  __shared__ float c1L[64], c2L[64];
  __shared__ float ytL[DIM];                        // 2 KB
  __shared__ float asL[HID];                        // 8 KB
  __shared__ float dyp[16][17];
  __shared__ int bcast[2];
  // static LDS ~61.6 KB -> exactly 2 wg/CU -> 64 wg/XCD (pigeonhole)

  const int t = threadIdx.x;
  if (t == 0) {
    int x;
    asm volatile("s_getreg_b32 %0, hwreg(HW_REG_XCC_ID)" : "=s"(x));
    x &= 7;
    bcast[0] = x;
    bcast[1] = atomicAdd(&ctrl[x], 1);
  }
  __syncthreads();
  const int xcd = bcast[0];
  const int sl  = bcast[1] & 63;
  const int grp = xcd * 2 + (sl >> 5);      // 16 groups of 32 wgs
  const bool lead = (sl & 31) == 0;
  int* arr = ctrl + 64 + grp * 64;
  int* gen = arr + 32;

  const int w = t >> 6, lane = t & 63, quad = lane >> 4, l16 = lane & 15;
  const int msub = w & 1, kpar = w >> 1;
  const int mA = xcd * 64 + (sl >> 5) * 32;         // group's 32 rows
  const int nA = (sl & 31) * 64;                    // gemm1 col tile
  const int nB = (sl & 31) * 16;                    // gemm2 col tile == y cols
  float* ytx = yts + grp * DIM;
  float* asx = a_ss + grp * HID;

  f32x4 DyR = {0.f,0.f,0.f,0.f}, K1 = DyR, K2 = DyR, K3 = DyR;
  float yR = 0.f, kd1 = 0.f, kd2 = 0.f, kd3 = 0.f;
  const int erow0 = mA + msub * 16 + quad * 4;
  const int ecol  = nB + l16;

  // load/store index helpers
  const int rA = t >> 3, cA = (t & 7) * 16;         // A tiles 32x128, 16 shorts/thread
  const int rB = t >> 2, cB = (t & 3) * 32;         // phase A B 64x128, 32 shorts/thread
  const int rB2 = t >> 4, cB2 = (t & 15) * 8;       // phase B B 16x128, 8 shorts/thread
  const int hcol = t & 63, hseg = t >> 6;           // h-accum: 4 thr/col
  const int dcol = t & 15, dseg = t >> 4;           // dy-accum: 16 thr/col
  const int wm = msub * 16, wn = kpar * 32;

  // ---- init ----
  if (kpar == 0) {
    for (int r = 0; r < 4; ++r) {
      float v = Dy0[(size_t)(erow0 + r) * DIM + ecol];
      DyR[r] = v;
      Vbuf[(size_t)(erow0 + r) * DIM + ecol] = f2bfu(v);
      out[DIM + (size_t)(erow0 + r) * DIM + ecol] = v;
    }
  }
  if (t < 16) {
    float v = y0[nB + t];
    yR = v;
    ytx[nB + t] = v;
    if (grp == 0) out[nB + t] = v;
  }
  int barid = 1;
  xbar(arr, gen, barid++, lead);

  for (int ss = 0; ss < 16; ++ss) {
    for (int st = 0; st < 4; ++st) {
      const float cn = (st == 2) ? DT : 0.5f * DT;
      // ================= PHASE A : g = V @ W1t^T (+ fused h-matvec) ===========
      {
        u64 q = ald64(ytx + t * 2);
        ytL[t * 2]     = __uint_as_float((unsigned)q);
        ytL[t * 2 + 1] = __uint_as_float((unsigned)(q >> 32));
      }
      {
        size_t aoff = (size_t)(mA + rA) * DIM + cA;
        size_t boff = (size_t)(nA + rB) * DIM + cB;
        u64 qa[2][4]; uint4 qb[2][4];
#pragma unroll
        for (int pp = 0; pp < 2; ++pp) {
          size_t ao = aoff + (size_t)pp * 128, bo = boff + (size_t)pp * 128;
          qa[pp][0] = ald64(Vbuf + ao);     qa[pp][1] = ald64(Vbuf + ao + 4);
          qa[pp][2] = ald64(Vbuf + ao + 8); qa[pp][3] = ald64(Vbuf + ao + 12);
          qb[pp][0] = *(const uint4*)&W1t[bo];      qb[pp][1] = *(const uint4*)&W1t[bo + 8];
          qb[pp][2] = *(const uint4*)&W1t[bo + 16]; qb[pp][3] = *(const uint4*)&W1t[bo + 24];
        }
        f32x4 acc0 = {0.f,0.f,0.f,0.f}, acc1 = acc0;
        float hs = 0.f;
        const int sa0 = swz(rA, cA), sa1 = swz(rA, cA + 8);
        const int sb0 = swz(rB, cB), sb1 = swz(rB, cB + 8);
        const int sb2 = swz(rB, cB + 16), sb3 = swz(rB, cB + 24);
#pragma unroll
        for (int c = 0; c < 4; ++c) {
          const int buf = c & 1;
          *(u64*)&As[buf][sa0]     = qa[buf][0]; *(u64*)&As[buf][sa0 + 4] = qa[buf][1];
          *(u64*)&As[buf][sa1]     = qa[buf][2]; *(u64*)&As[buf][sa1 + 4] = qa[buf][3];
          *(uint4*)&Bs[buf][sb0] = qb[buf][0]; *(uint4*)&Bs[buf][sb1] = qb[buf][1];
          *(uint4*)&Bs[buf][sb2] = qb[buf][2]; *(uint4*)&Bs[buf][sb3] = qb[buf][3];
          if (c < 2) {
            size_t ao = aoff + (size_t)(c + 2) * 128, bo = boff + (size_t)(c + 2) * 128;
            qa[buf][0] = ald64(Vbuf + ao);     qa[buf][1] = ald64(Vbuf + ao + 4);
            qa[buf][2] = ald64(Vbuf + ao + 8); qa[buf][3] = ald64(Vbuf + ao + 12);
            qb[buf][0] = *(const uint4*)&W1t[bo];      qb[buf][1] = *(const uint4*)&W1t[bo + 8];
            qb[buf][2] = *(const uint4*)&W1t[bo + 16]; qb[buf][3] = *(const uint4*)&W1t[bo + 24];
          }
          __syncthreads();
#pragma unroll
          for (int kk = 0; kk < 128; kk += 32) {
            short8 a   = *(const short8*)&As[buf][swz(wm + l16, kk + quad * 8)];
            short8 b0  = *(const short8*)&Bs[buf][swz(wn + l16, kk + quad * 8)];
            short8 b1v = *(const short8*)&Bs[buf][swz(wn + 16 + l16, kk + quad * 8)];
            acc0 = __builtin_amdgcn_mfma_f32_16x16x32_bf16(a, b0, acc0, 0, 0, 0);
            acc1 = __builtin_amdgcn_mfma_f32_16x16x32_bf16(a, b1v, acc1, 0, 0, 0);
          }
#pragma unroll
          for (int g = 0; g < 4; ++g) {
            uint4 wq = *(const uint4*)&Bs[buf][swz(hcol, hseg * 32 + g * 8)];
            hs += dot8(wq, &ytL[c * 128 + hseg * 32 + g * 8]);
          }
        }
        // h reduce -> tanh -> c1/c2, a_s
        paccL[hseg * 64 + hcol] = hs;
        __syncthreads();
        if (t < 64) {
          float hsum = paccL[t] + paccL[64 + t] + paccL[128 + t] + paccL[192 + t] + b1[nA + t];
          float a = tanhf(hsum);
          float ap = 1.f - a * a;
          c1L[t] = ap; c2L[t] = -a * ap;
          asx[nA + t] = a;
        }
        __syncthreads();
        // epilogue: transform + store tbuf
        int row0 = mA + wm + quad * 4;
        int c0i = wn + l16, c1i = wn + 16 + l16;
        float C1a = c1L[c0i], C2a = c2L[c0i], C1b = c1L[c1i], C2b = c2L[c1i];
#pragma unroll
        for (int r = 0; r < 4; ++r) {
          float g0 = acc0[r], g1 = acc1[r];
          tbuf[(size_t)(row0 + r) * HID + nA + c0i] = f2bfu(g0 * (C1a + C2a * g0));
          tbuf[(size_t)(row0 + r) * HID + nA + c1i] = f2bfu(g1 * (C1b + C2b * g1));
        }
      }
      xbar(arr, gen, barid++, lead);
      // ================= PHASE B : dDy = t @ W2t^T (+ fused dy-matvec) ========
      {
#pragma unroll
        for (int i = 0; i < 4; ++i) {
          u64 q = ald64(asx + t * 8 + i * 2);
          asL[t * 8 + i * 2]     = __uint_as_float((unsigned)q);
          asL[t * 8 + i * 2 + 1] = __uint_as_float((unsigned)(q >> 32));
        }
        size_t aoff = (size_t)(mA + rA) * HID + cA;
        size_t boff = (size_t)(nB + rB2) * HID + cB2;
        u64 pa[2][4]; uint4 pb[2];
#pragma unroll
        for (int pp = 0; pp < 2; ++pp) {
          size_t ao = aoff + (size_t)pp * 128;
          pa[pp][0] = ald64(tbuf + ao);     pa[pp][1] = ald64(tbuf + ao + 4);
          pa[pp][2] = ald64(tbuf + ao + 8); pa[pp][3] = ald64(tbuf + ao + 12);
          pb[pp] = *(const uint4*)&W2t[boff + (size_t)pp * 128];
        }
        f32x4 acc = {0.f,0.f,0.f,0.f};
        float dys = 0.f;
        const int sa0 = swz(rA, cA), sa1 = swz(rA, cA + 8);
        const int sb0 = swz(rB2, cB2);
        const int sdy = swz(dcol, dseg * 8);
#pragma unroll 2
        for (int c = 0; c < 16; ++c) {
          const int buf = c & 1;
          *(u64*)&As[buf][sa0]     = pa[buf][0]; *(u64*)&As[buf][sa0 + 4] = pa[buf][1];
          *(u64*)&As[buf][sa1]     = pa[buf][2]; *(u64*)&As[buf][sa1 + 4] = pa[buf][3];
          *(uint4*)&Bs[buf][sb0] = pb[buf];
          if (c < 14) {
            size_t ao = aoff + (size_t)(c + 2) * 128;
            pa[buf][0] = ald64(tbuf + ao);     pa[buf][1] = ald64(tbuf + ao + 4);
            pa[buf][2] = ald64(tbuf + ao + 8); pa[buf][3] = ald64(tbuf + ao + 12);
            pb[buf] = *(const uint4*)&W2t[boff + (size_t)(c + 2) * 128];
          }
          __syncthreads();
          if ((c & 1) == kpar) {
#pragma unroll
            for (int kk = 0; kk < 128; kk += 32) {
              short8 a = *(const short8*)&As[buf][swz(msub * 16 + l16, kk + quad * 8)];
              short8 b = *(const short8*)&Bs[buf][swz(l16, kk + quad * 8)];
              acc = __builtin_amdgcn_mfma_f32_16x16x32_bf16(a, b, acc, 0, 0, 0);
            }
          }
          {
            uint4 wq = *(const uint4*)&Bs[buf][sdy];
            dys += dot8(wq, &asL[c * 128 + dseg * 8]);
          }
        }
        // reductions
        if (kpar == 1)
          for (int r = 0; r < 4; ++r) paccL[(msub * 64 + lane) * 4 + r] = acc[r];
        dyp[dseg][dcol] = dys;
        __syncthreads();
        if (kpar == 0) {
          f32x4 o = acc;
          for (int r = 0; r < 4; ++r) o[r] += paccL[(msub * 64 + lane) * 4 + r];
          if (st == 0) K1 = o; else if (st == 1) K2 = o; else if (st == 2) K3 = o;
          if (st < 3) {
            for (int r = 0; r < 4; ++r) {
              float v = DyR[r] + cn * o[r];
              Vbuf[(size_t)(erow0 + r) * DIM + ecol] = f2bfu(v);
            }
          } else {
            const float dt6 = DT / 6.f;
            for (int r = 0; r < 4; ++r) {
              float v = DyR[r] + dt6 * (K1[r] + 2.f * K2[r] + 2.f * K3[r] + o[r]);
              DyR[r] = v;
              Vbuf[(size_t)(erow0 + r) * DIM + ecol] = f2bfu(v);
              if (ss & 1) out[(size_t)(ss / 2 + 1) * ROWSZ + DIM + (size_t)(erow0 + r) * DIM + ecol] = v;
            }
          }
        }
        if (t < 16) {
          float r0 = 0.f;
#pragma unroll
          for (int q2 = 0; q2 < 16; ++q2) r0 += dyp[q2][t];
          float k4 = r0 + b2[nB + t];
          if (st == 0) kd1 = k4; else if (st == 1) kd2 = k4; else if (st == 2) kd3 = k4;
          if (st < 3) {
            ytx[nB + t] = yR + cn * k4;
          } else {
            yR += (DT / 6.f) * (kd1 + 2.f * kd2 + 2.f * kd3 + k4);
            ytx[nB + t] = yR;
            if ((ss & 1) && grp == 0) out[(size_t)(ss / 2 + 1) * ROWSZ + nB + t] = yR;
          }
        }
      }
      xbar(arr, gen, barid++, lead);
    }
  }
}

extern "C" void kernel_launch(void* const* d_in, const int* in_sizes, int n_in,
                              void* d_out, int out_size, void* d_ws, size_t ws_size,
                              hipStream_t stream) {
  const float* y0  = (const float*)d_in[1];
  const float* Dy0 = (const float*)d_in[2];
  const float* W1  = (const float*)d_in[3];
  const float* b1  = (const float*)d_in[4];
  const float* W2  = (const float*)d_in[5];
  const float* b2  = (const float*)d_in[6];
  float* out = (float*)d_out;

  char* p = (char*)d_ws;
  auto alloc = [&](size_t bytes) {
    char* r = p;
    p += (bytes + 255) & ~(size_t)255;
    return r;
  };
  unsigned short* W1t  = (unsigned short*)alloc((size_t)HID * DIM * 2);
  unsigned short* W2t  = (unsigned short*)alloc((size_t)DIM * HID * 2);
  unsigned short* Vbuf = (unsigned short*)alloc((size_t)DIM * DIM * 2);
  unsigned short* tbuf = (unsigned short*)alloc((size_t)DIM * HID * 2);
  float* yts  = (float*)alloc(16 * DIM * 4);
  float* a_ss = (float*)alloc(16 * HID * 4);
  int* ctrl   = (int*)alloc(8192);

  hipMemsetAsync(ctrl, 0, 8192, stream);
  k_transpose_bf16<<<dim3(HID / 32, DIM / 32), 256, 0, stream>>>(W1, (__hip_bfloat16*)W1t, DIM, HID);
  k_transpose_bf16<<<dim3(DIM / 32, HID / 32), 256, 0, stream>>>(W2, (__hip_bfloat16*)W2t, HID, DIM);
  k_persist<<<512, 256, 0, stream>>>(y0, Dy0, W1t, W2t, b1, b2,
                                     Vbuf, tbuf, yts, a_ss, ctrl, out);
}

// Round 7
// 1552.860 us; speedup vs baseline: 3.0589x; 1.4994x over previous
//
#include <hip/hip_runtime.h>
#include <hip/hip_bf16.h>

typedef __attribute__((ext_vector_type(8))) short short8;
typedef float f32x4 __attribute__((ext_vector_type(4)));
typedef unsigned long long u64;

#define DIM 512
#define HID 2048
#define ROWSZ (513*512)
#define DT 0.0625f

#define WAITV(n) asm volatile("s_waitcnt vmcnt(" #n ")" ::: "memory")
#define SBAR()   asm volatile("s_barrier" ::: "memory")
typedef const __attribute__((address_space(1))) void* gas1;
typedef __attribute__((address_space(3))) void* las3;
// aux bit0 = SC0 on gfx94x/gfx950: bypass L1, serve from XCD L2 (coherence point for same-XCD producers)
#define GLL16(g,l,aux) __builtin_amdgcn_global_load_lds((gas1)(g),(las3)(l),16,0,aux)
#define GLL4(g,l,aux)  __builtin_amdgcn_global_load_lds((gas1)(g),(las3)(l),4,0,aux)

__device__ __forceinline__ float bf2f(unsigned short s){ return __uint_as_float(((unsigned)s)<<16); }
__device__ __forceinline__ unsigned short f2bfu(float f){ __hip_bfloat16 h=__float2bfloat16(f); return *(unsigned short*)&h; }
__device__ __forceinline__ float dot8(uint4 wq, const float* a){
  const unsigned short* ws=(const unsigned short*)&wq;
  float s=0.f;
#pragma unroll
  for(int i=0;i<8;++i) s += bf2f(ws[i])*a[i];
  return s;
}

// group barrier: 32 wgs (XCD-local), relaxed agent atomics, no cache maintenance
__device__ __forceinline__ void xbar(int* arr, int* gen, int target, bool lead){
  asm volatile("s_waitcnt vmcnt(0) lgkmcnt(0)" ::: "memory");
  __syncthreads();
  if (threadIdx.x == 0){
    __hip_atomic_fetch_add(arr, 1, __ATOMIC_RELAXED, __HIP_MEMORY_SCOPE_AGENT);
    if (lead){
      while (__hip_atomic_load(arr, __ATOMIC_RELAXED, __HIP_MEMORY_SCOPE_AGENT) < 32*target)
        __builtin_amdgcn_s_sleep(2);
      __hip_atomic_store(gen, target, __ATOMIC_RELAXED, __HIP_MEMORY_SCOPE_AGENT);
    } else {
      while (__hip_atomic_load(gen, __ATOMIC_RELAXED, __HIP_MEMORY_SCOPE_AGENT) < target)
        __builtin_amdgcn_s_sleep(8);
    }
  }
  __syncthreads();
}

__global__ void k_transpose_bf16(const float* __restrict__ src,
                                 __hip_bfloat16* __restrict__ dst, int R, int C) {
  __shared__ float tile[32][33];
  int c0 = blockIdx.x * 32, r0 = blockIdx.y * 32;
  int tx = threadIdx.x & 31, ty = threadIdx.x >> 5;
  for (int i = 0; i < 32; i += 8)
    tile[ty + i][tx] = src[(size_t)(r0 + ty + i) * C + c0 + tx];
  __syncthreads();
  for (int i = 0; i < 32; i += 8)
    dst[(size_t)(c0 + ty + i) * R + r0 + tx] = __float2bfloat16(tile[tx][ty + i]);
}

__global__ __launch_bounds__(256, 2) void k_persist(
    const float* __restrict__ y0, const float* __restrict__ Dy0,
    const unsigned short* __restrict__ W1t, const unsigned short* __restrict__ W2t,
    const float* __restrict__ b1, const float* __restrict__ b2,
    unsigned short* __restrict__ Vbuf, unsigned short* __restrict__ tbuf,
    float* __restrict__ yts, float* __restrict__ a_ss,
    int* __restrict__ ctrl, float* __restrict__ out) {
  __shared__ __align__(16) short tiles[5 * 6144];   // 60 KB: 5-buffer ring, 12 KB each
  __shared__ float asL[HID];                        // 8 KB
  __shared__ float ytL[DIM];                        // 2 KB
  __shared__ float paccL[512];                      // 2 KB
  __shared__ float c1L[64], c2L[64];
  __shared__ float dyp[16][17];
  __shared__ int bcast[2];
  // ~75.3 KB total -> exactly 2 wg/CU -> 64 wg/XCD (pigeonhole)

  const int t = threadIdx.x;
  if (t == 0) {
    int x;
    asm volatile("s_getreg_b32 %0, hwreg(HW_REG_XCC_ID)" : "=s"(x));
    x &= 7;
    bcast[0] = x;
    bcast[1] = atomicAdd(&ctrl[x], 1);
  }
  __syncthreads();
  const int xcd = bcast[0];
  const int sl  = bcast[1] & 63;
  const int grp = xcd * 2 + (sl >> 5);
  const bool lead = (sl & 31) == 0;
  int* arr = ctrl + 64 + grp * 64;
  int* gen = arr + 32;

  const int w = t >> 6, lane = t & 63, quad = lane >> 4, l16 = lane & 15;
  const int msub = w & 1, kpar = w >> 1;
  const int wm = msub * 16, wn = kpar * 32;
  const int mA = xcd * 64 + (sl >> 5) * 32;
  const int nA = (sl & 31) * 64;
  const int nB = (sl & 31) * 16;
  float* ytx = yts + grp * DIM;
  float* asx = a_ss + grp * HID;

  const int hcol = t & 63, hseg = t >> 6;
  const int dcol = t & 15, dseg = t >> 4;

  f32x4 DyR = {0.f,0.f,0.f,0.f}, K1 = DyR, K2 = DyR, K3 = DyR;
  float yR = 0.f, kd1 = 0.f, kd2 = 0.f, kd3 = 0.f;
  const int erow0 = mA + msub * 16 + quad * 4;
  const int ecol  = nB + l16;

  // staging lambdas (lds base wave-uniform; HW scatters lane*16B)
  auto issueA = [&](int buf, int c) {
    short* tA = tiles + buf * 6144;        // 32x64 shorts
    short* tB = tA + 2048;                 // 64x64 shorts
    int k0 = c * 64;
    GLL16(Vbuf + (size_t)(mA + w * 8 + (lane >> 3)) * DIM + k0 + (lane & 7) * 8,
          tA + (w * 8) * 64, 1);
    GLL16(W1t + (size_t)(nA + w * 16 + (lane >> 3)) * DIM + k0 + (lane & 7) * 8,
          tB + (w * 16) * 64, 0);
    GLL16(W1t + (size_t)(nA + w * 16 + 8 + (lane >> 3)) * DIM + k0 + (lane & 7) * 8,
          tB + (w * 16 + 8) * 64, 0);
  };
  auto issueB = [&](int buf, int c) {
    short* tA = tiles + buf * 6144;        // 32x128 shorts
    short* tB = tA + 4096;                 // 16x128 shorts
    int k0 = c * 128;
    GLL16(tbuf + (size_t)(mA + w * 8 + (lane >> 4)) * HID + k0 + (lane & 15) * 8,
          tA + (w * 8) * 128, 1);
    GLL16(tbuf + (size_t)(mA + w * 8 + 4 + (lane >> 4)) * HID + k0 + (lane & 15) * 8,
          tA + (w * 8 + 4) * 128, 1);
    GLL16(W2t + (size_t)(nB + w * 4 + (lane >> 4)) * HID + k0 + (lane & 15) * 8,
          tB + (w * 4) * 128, 0);
  };

  // ---- init ----
  if (kpar == 0) {
    for (int r = 0; r < 4; ++r) {
      float v = Dy0[(size_t)(erow0 + r) * DIM + ecol];
      DyR[r] = v;
      Vbuf[(size_t)(erow0 + r) * DIM + ecol] = f2bfu(v);
      out[DIM + (size_t)(erow0 + r) * DIM + ecol] = v;
    }
  }
  if (t < 16) {
    float v = y0[nB + t];
    yR = v;
    ytx[nB + t] = v;
    if (grp == 0) out[nB + t] = v;
  }
  int barid = 1;
  xbar(arr, gen, barid++, lead);

  for (int ss = 0; ss < 16; ++ss) {
    for (int st = 0; st < 4; ++st) {
      const float cn = (st == 2) ? DT : 0.5f * DT;
      // ========== PHASE A: g = V @ W1t^T (+ fused h-matvec) ==========
      {
        // pre-issue: ytL (2) + chunks 0..2 (9)
        GLL4(ytx + w * 128 + lane,      &ytL[w * 128], 1);
        GLL4(ytx + w * 128 + 64 + lane, &ytL[w * 128 + 64], 1);
        issueA(0, 0); issueA(1, 1); issueA(2, 2);
        f32x4 acc0 = {0.f,0.f,0.f,0.f}, acc1 = acc0;
        float hs = 0.f;
        int cb = 0, ic = 3;
        for (int c = 0; c < 8; ++c) {
          if (c < 5) { issueA(ic, c + 3); ic = (ic == 4) ? 0 : ic + 1; }
          if (c < 5) { WAITV(9); } else if (c == 5) { WAITV(6); }
          else if (c == 6) { WAITV(3); } else { WAITV(0); }
          SBAR();
          const short* tA = tiles + cb * 6144;
          const short* tB = tA + 2048;
#pragma unroll
          for (int kk = 0; kk < 64; kk += 32) {
            short8 a   = *(const short8*)&tA[(wm + l16) * 64 + kk + quad * 8];
            short8 b0  = *(const short8*)&tB[(wn + l16) * 64 + kk + quad * 8];
            short8 b1v = *(const short8*)&tB[(wn + 16 + l16) * 64 + kk + quad * 8];
            acc0 = __builtin_amdgcn_mfma_f32_16x16x32_bf16(a, b0, acc0, 0, 0, 0);
            acc1 = __builtin_amdgcn_mfma_f32_16x16x32_bf16(a, b1v, acc1, 0, 0, 0);
          }
#pragma unroll
          for (int g = 0; g < 2; ++g) {
            uint4 wq = *(const uint4*)&tB[hcol * 64 + hseg * 16 + g * 8];
            hs += dot8(wq, &ytL[c * 64 + hseg * 16 + g * 8]);
          }
          cb = (cb == 4) ? 0 : cb + 1;
        }
        paccL[hseg * 64 + hcol] = hs;
        __syncthreads();
        if (t < 64) {
          float hsum = paccL[t] + paccL[64 + t] + paccL[128 + t] + paccL[192 + t] + b1[nA + t];
          float a = tanhf(hsum);
          float ap = 1.f - a * a;
          c1L[t] = ap; c2L[t] = -a * ap;
          asx[nA + t] = a;
        }
        __syncthreads();
        int row0 = mA + wm + quad * 4;
        int c0i = wn + l16, c1i = wn + 16 + l16;
        float C1a = c1L[c0i], C2a = c2L[c0i], C1b = c1L[c1i], C2b = c2L[c1i];
#pragma unroll
        for (int r = 0; r < 4; ++r) {
          float g0 = acc0[r], g1 = acc1[r];
          tbuf[(size_t)(row0 + r) * HID + nA + c0i] = f2bfu(g0 * (C1a + C2a * g0));
          tbuf[(size_t)(row0 + r) * HID + nA + c1i] = f2bfu(g1 * (C1b + C2b * g1));
        }
      }
      xbar(arr, gen, barid++, lead);
      // ========== PHASE B: dDy = t @ W2t^T (+ fused dy-matvec) ==========
      {
        GLL16(asx + w * 512 + lane * 4,       &asL[w * 512], 1);
        GLL16(asx + w * 512 + 256 + lane * 4, &asL[w * 512 + 256], 1);
        issueB(0, 0); issueB(1, 1); issueB(2, 2);
        f32x4 acc = {0.f,0.f,0.f,0.f};
        float dys = 0.f;
        int cb = 0, ic = 3;
        for (int c = 0; c < 16; ++c) {
          if (c < 13) { issueB(ic, c + 3); ic = (ic == 4) ? 0 : ic + 1; }
          if (c < 13) { WAITV(9); } else if (c == 13) { WAITV(6); }
          else if (c == 14) { WAITV(3); } else { WAITV(0); }
          SBAR();
          const short* tA = tiles + cb * 6144;
          const short* tB = tA + 4096;
#pragma unroll
          for (int kk = 0; kk < 64; kk += 32) {
            short8 a = *(const short8*)&tA[(msub * 16 + l16) * 128 + kpar * 64 + kk + quad * 8];
            short8 b = *(const short8*)&tB[l16 * 128 + kpar * 64 + kk + quad * 8];
            acc = __builtin_amdgcn_mfma_f32_16x16x32_bf16(a, b, acc, 0, 0, 0);
          }
          uint4 wq = *(const uint4*)&tB[dcol * 128 + dseg * 8];
          dys += dot8(wq, &asL[c * 128 + dseg * 8]);
          cb = (cb == 4) ? 0 : cb + 1;
        }
        if (kpar == 1)
          for (int r = 0; r < 4; ++r) paccL[(msub * 64 + lane) * 4 + r] = acc[r];
        dyp[dseg][dcol] = dys;
        __syncthreads();
        if (kpar == 0) {
          f32x4 o = acc;
          for (int r = 0; r < 4; ++r) o[r] += paccL[(msub * 64 + lane) * 4 + r];
          if (st == 0) K1 = o; else if (st == 1) K2 = o; else if (st == 2) K3 = o;
          if (st < 3) {
            for (int r = 0; r < 4; ++r) {
              float v = DyR[r] + cn * o[r];
              Vbuf[(size_t)(erow0 + r) * DIM + ecol] = f2bfu(v);
            }
          } else {
            const float dt6 = DT / 6.f;
            for (int r = 0; r < 4; ++r) {
              float v = DyR[r] + dt6 * (K1[r] + 2.f * K2[r] + 2.f * K3[r] + o[r]);
              DyR[r] = v;
              Vbuf[(size_t)(erow0 + r) * DIM + ecol] = f2bfu(v);
              if (ss & 1) out[(size_t)(ss / 2 + 1) * ROWSZ + DIM + (size_t)(erow0 + r) * DIM + ecol] = v;
            }
          }
        }
        if (t < 16) {
          float r0 = 0.f;
#pragma unroll
          for (int q2 = 0; q2 < 16; ++q2) r0 += dyp[q2][t];
          float k4 = r0 + b2[nB + t];
          if (st == 0) kd1 = k4; else if (st == 1) kd2 = k4; else if (st == 2) kd3 = k4;
          if (st < 3) {
            ytx[nB + t] = yR + cn * k4;
          } else {
            yR += (DT / 6.f) * (kd1 + 2.f * kd2 + 2.f * kd3 + k4);
            ytx[nB + t] = yR;
            if ((ss & 1) && grp == 0) out[(size_t)(ss / 2 + 1) * ROWSZ + nB + t] = yR;
          }
        }
      }
      xbar(arr, gen, barid++, lead);
    }
  }
}

extern "C" void kernel_launch(void* const* d_in, const int* in_sizes, int n_in,
                              void* d_out, int out_size, void* d_ws, size_t ws_size,
                              hipStream_t stream) {
  const float* y0  = (const float*)d_in[1];
  const float* Dy0 = (const float*)d_in[2];
  const float* W1  = (const float*)d_in[3];
  const float* b1  = (const float*)d_in[4];
  const float* W2  = (const float*)d_in[5];
  const float* b2  = (const float*)d_in[6];
  float* out = (float*)d_out;

  char* p = (char*)d_ws;
  auto alloc = [&](size_t bytes) {
    char* r = p;
    p += (bytes + 255) & ~(size_t)255;
    return r;
  };
  unsigned short* W1t  = (unsigned short*)alloc((size_t)HID * DIM * 2);
  unsigned short* W2t  = (unsigned short*)alloc((size_t)DIM * HID * 2);
  unsigned short* Vbuf = (unsigned short*)alloc((size_t)DIM * DIM * 2);
  unsigned short* tbuf = (unsigned short*)alloc((size_t)DIM * HID * 2);
  float* yts  = (float*)alloc(16 * DIM * 4);
  float* a_ss = (float*)alloc(16 * HID * 4);
  int* ctrl   = (int*)alloc(8192);

  hipMemsetAsync(ctrl, 0, 8192, stream);
  k_transpose_bf16<<<dim3(HID / 32, DIM / 32), 256, 0, stream>>>(W1, (__hip_bfloat16*)W1t, DIM, HID);
  k_transpose_bf16<<<dim3(DIM / 32, HID / 32), 256, 0, stream>>>(W2, (__hip_bfloat16*)W2t, HID, DIM);
  k_persist<<<512, 256, 0, stream>>>(y0, Dy0, W1t, W2t, b1, b2,
                                     Vbuf, tbuf, yts, a_ss, ctrl, out);
}

// Round 8
// 1133.007 us; speedup vs baseline: 4.1924x; 1.3706x over previous
//
#include <hip/hip_runtime.h>
#include <hip/hip_bf16.h>

typedef __attribute__((ext_vector_type(8))) short short8;
typedef float f32x4 __attribute__((ext_vector_type(4)));
typedef unsigned long long u64;

#define DIM 512
#define HID 2048
#define ROWSZ (513*512)
#define DT 0.0625f

#define WAITV(n) asm volatile("s_waitcnt vmcnt(" #n ")" ::: "memory")
#define SBAR()   asm volatile("s_barrier" ::: "memory")
typedef const __attribute__((address_space(1))) void* gas1;
typedef __attribute__((address_space(3))) void* las3;
// aux bit0 = SC0: bypass L1, serve from XCD L2 (coherence point for same-XCD producers)
#define GLL16(g,l,aux) __builtin_amdgcn_global_load_lds((gas1)(g),(las3)(l),16,0,aux)
#define GLL4(g,l,aux)  __builtin_amdgcn_global_load_lds((gas1)(g),(las3)(l),4,0,aux)

__device__ __forceinline__ float bf2f(unsigned short s){ return __uint_as_float(((unsigned)s)<<16); }
__device__ __forceinline__ unsigned short f2bfu(float f){ __hip_bfloat16 h=__float2bfloat16(f); return *(unsigned short*)&h; }
__device__ __forceinline__ float dot8(uint4 wq, const float* a){
  const unsigned short* ws=(const unsigned short*)&wq;
  float s=0.f;
#pragma unroll
  for(int i=0;i<8;++i) s += bf2f(ws[i])*a[i];
  return s;
}

// group barrier: 32 wgs (XCD-local), relaxed agent atomics, no cache maintenance
__device__ __forceinline__ void xbar(int* arr, int* gen, int target, bool lead){
  asm volatile("s_waitcnt vmcnt(0) lgkmcnt(0)" ::: "memory");
  __syncthreads();
  if (threadIdx.x == 0){
    __hip_atomic_fetch_add(arr, 1, __ATOMIC_RELAXED, __HIP_MEMORY_SCOPE_AGENT);
    if (lead){
      while (__hip_atomic_load(arr, __ATOMIC_RELAXED, __HIP_MEMORY_SCOPE_AGENT) < 32*target)
        __builtin_amdgcn_s_sleep(2);
      __hip_atomic_store(gen, target, __ATOMIC_RELAXED, __HIP_MEMORY_SCOPE_AGENT);
    } else {
      while (__hip_atomic_load(gen, __ATOMIC_RELAXED, __HIP_MEMORY_SCOPE_AGENT) < target)
        __builtin_amdgcn_s_sleep(4);
    }
  }
  __syncthreads();
}

__global__ void k_transpose_bf16(const float* __restrict__ src,
                                 __hip_bfloat16* __restrict__ dst, int R, int C) {
  __shared__ float tile[32][33];
  int c0 = blockIdx.x * 32, r0 = blockIdx.y * 32;
  int tx = threadIdx.x & 31, ty = threadIdx.x >> 5;
  for (int i = 0; i < 32; i += 8)
    tile[ty + i][tx] = src[(size_t)(r0 + ty + i) * C + c0 + tx];
  __syncthreads();
  for (int i = 0; i < 32; i += 8)
    dst[(size_t)(c0 + ty + i) * R + r0 + tx] = __float2bfloat16(tile[tx][ty + i]);
}

__global__ __launch_bounds__(256, 2) void k_persist(
    const float* __restrict__ y0, const float* __restrict__ Dy0,
    const unsigned short* __restrict__ W1t, const unsigned short* __restrict__ W2t,
    const float* __restrict__ b1, const float* __restrict__ b2,
    unsigned short* __restrict__ Vbuf, unsigned short* __restrict__ tbuf,
    float* __restrict__ yts, float* __restrict__ a_ss,
    int* __restrict__ ctrl, float* __restrict__ out) {
  __shared__ __align__(16) short tiles[5 * 6144];   // 60 KB: 5-buffer ring, 12 KB each
  __shared__ float asL[HID];                        // 8 KB
  __shared__ float ytL[DIM];                        // 2 KB
  __shared__ float paccL[512];                      // 2 KB
  __shared__ float c1L[64], c2L[64];
  __shared__ float dyp[16][17];
  __shared__ int bcast[2];
  // ~75.3 KB total -> exactly 2 wg/CU -> 64 wg/XCD (pigeonhole)

  const int t = threadIdx.x;
  if (t == 0) {
    int x;
    asm volatile("s_getreg_b32 %0, hwreg(HW_REG_XCC_ID)" : "=s"(x));
    x &= 7;
    bcast[0] = x;
    bcast[1] = atomicAdd(&ctrl[x], 1);
  }
  __syncthreads();
  const int xcd = bcast[0];
  const int sl  = bcast[1] & 63;
  const int grp = xcd * 2 + (sl >> 5);
  const bool lead = (sl & 31) == 0;
  int* arr = ctrl + 64 + grp * 64;
  int* gen = arr + 32;

  const int w = t >> 6, lane = t & 63, quad = lane >> 4, l16 = lane & 15;
  const int msub = w & 1, kpar = w >> 1;
  const int wm = msub * 16, wn = kpar * 32;
  const int mA = xcd * 64 + (sl >> 5) * 32;
  const int nA = (sl & 31) * 64;
  const int nB = (sl & 31) * 16;
  float* ytx = yts + grp * DIM;
  float* asx = a_ss + grp * HID;

  const int hcol = t & 63, hseg = t >> 6;
  const int dcol = t & 15, dseg = t >> 4;
  const int l7 = l16 & 7;

  f32x4 DyR = {0.f,0.f,0.f,0.f}, K1 = DyR, K2 = DyR, K3 = DyR;
  float yR = 0.f, kd1 = 0.f, kd2 = 0.f, kd3 = 0.f;
  const int erow0 = mA + msub * 16 + quad * 4;
  const int ecol  = nB + l16;

  // ---- swizzled DMA staging ----
  // XOR-swizzle: 16B granule g at row r is stored at physical granule g^(r&7)
  // (phase B, 16 granules/row: swizzle low 3 bits only). DMA scatter is fixed
  // (lane*16B), so we permute the GLOBAL source column instead.
  auto issueA = [&](int buf, int c) {
    short* tA = tiles + buf * 6144;        // 32x64 shorts
    short* tB = tA + 2048;                 // 64x64 shorts
    int k0 = c * 64;
    int r8 = lane >> 3;
    int gsw = ((lane & 7) ^ r8) * 8;
    GLL16(Vbuf + (size_t)(mA + w * 8 + r8) * DIM + k0 + gsw,      tA + (w * 8) * 64, 1);
    GLL16(W1t + (size_t)(nA + w * 16 + r8) * DIM + k0 + gsw,      tB + (w * 16) * 64, 0);
    GLL16(W1t + (size_t)(nA + w * 16 + 8 + r8) * DIM + k0 + gsw,  tB + (w * 16 + 8) * 64, 0);
  };
  auto issueB = [&](int buf, int c) {
    short* tA = tiles + buf * 6144;        // 32x128 shorts
    short* tB = tA + 4096;                 // 16x128 shorts
    int k0 = c * 128;
    int r16 = lane >> 4;
    int gA0 = ((lane & 8) | ((lane & 7) ^ (r16 & 7))) * 8;
    int gA1 = ((lane & 8) | ((lane & 7) ^ ((4 + r16) & 7))) * 8;
    int gB  = ((lane & 8) | ((lane & 7) ^ ((w * 4 + r16) & 7))) * 8;
    GLL16(tbuf + (size_t)(mA + w * 8 + r16) * HID + k0 + gA0,     tA + (w * 8) * 128, 1);
    GLL16(tbuf + (size_t)(mA + w * 8 + 4 + r16) * HID + k0 + gA1, tA + (w * 8 + 4) * 128, 1);
    GLL16(W2t + (size_t)(nB + w * 4 + r16) * HID + k0 + gB,       tB + (w * 4) * 128, 0);
  };

  // ---- init ----
  if (kpar == 0) {
    for (int r = 0; r < 4; ++r) {
      float v = Dy0[(size_t)(erow0 + r) * DIM + ecol];
      DyR[r] = v;
      Vbuf[(size_t)(erow0 + r) * DIM + ecol] = f2bfu(v);
      out[DIM + (size_t)(erow0 + r) * DIM + ecol] = v;
    }
  }
  if (t < 16) {
    float v = y0[nB + t];
    yR = v;
    ytx[nB + t] = v;
    if (grp == 0) out[nB + t] = v;
  }
  int barid = 1;
  xbar(arr, gen, barid++, lead);

  for (int ss = 0; ss < 16; ++ss) {
    for (int st = 0; st < 4; ++st) {
      const float cn = (st == 2) ? DT : 0.5f * DT;
      // ========== PHASE A: g = V @ W1t^T (+ fused h-matvec) ==========
      {
        GLL4(ytx + w * 128 + lane,      &ytL[w * 128], 1);
        GLL4(ytx + w * 128 + 64 + lane, &ytL[w * 128 + 64], 1);
        issueA(0, 0); issueA(1, 1); issueA(2, 2);
        f32x4 acc0 = {0.f,0.f,0.f,0.f}, acc1 = acc0;
        float hs = 0.f;
        int cb = 0, ic = 3;
        for (int c = 0; c < 8; ++c) {
          if (c < 5) { issueA(ic, c + 3); ic = (ic == 4) ? 0 : ic + 1; }
          if (c < 5) { WAITV(9); } else if (c == 5) { WAITV(6); }
          else if (c == 6) { WAITV(3); } else { WAITV(0); }
          SBAR();
          const short* tA = tiles + cb * 6144;
          const short* tB = tA + 2048;
#pragma unroll
          for (int kk = 0; kk < 64; kk += 32) {
            int gq = (kk >> 3) + quad;                 // logical granule 0..7
            int ps = ((gq ^ l7) << 3);
            short8 a   = *(const short8*)&tA[(wm + l16) * 64 + ps];
            short8 b0  = *(const short8*)&tB[(wn + l16) * 64 + ps];
            short8 b1v = *(const short8*)&tB[(wn + 16 + l16) * 64 + ps];
            acc0 = __builtin_amdgcn_mfma_f32_16x16x32_bf16(a, b0, acc0, 0, 0, 0);
            acc1 = __builtin_amdgcn_mfma_f32_16x16x32_bf16(a, b1v, acc1, 0, 0, 0);
          }
#pragma unroll
          for (int g = 0; g < 2; ++g) {
            int pg = ((hseg * 2 + g) ^ (hcol & 7)) << 3;
            uint4 wq = *(const uint4*)&tB[hcol * 64 + pg];
            hs += dot8(wq, &ytL[c * 64 + hseg * 16 + g * 8]);
          }
          cb = (cb == 4) ? 0 : cb + 1;
        }
        paccL[hseg * 64 + hcol] = hs;
        __syncthreads();
        if (t < 64) {
          float hsum = paccL[t] + paccL[64 + t] + paccL[128 + t] + paccL[192 + t] + b1[nA + t];
          float a = tanhf(hsum);
          float ap = 1.f - a * a;
          c1L[t] = ap; c2L[t] = -a * ap;
          asx[nA + t] = a;
        }
        __syncthreads();
        int row0 = mA + wm + quad * 4;
        int c0i = wn + l16, c1i = wn + 16 + l16;
        float C1a = c1L[c0i], C2a = c2L[c0i], C1b = c1L[c1i], C2b = c2L[c1i];
#pragma unroll
        for (int r = 0; r < 4; ++r) {
          float g0 = acc0[r], g1 = acc1[r];
          tbuf[(size_t)(row0 + r) * HID + nA + c0i] = f2bfu(g0 * (C1a + C2a * g0));
          tbuf[(size_t)(row0 + r) * HID + nA + c1i] = f2bfu(g1 * (C1b + C2b * g1));
        }
      }
      xbar(arr, gen, barid++, lead);
      // ========== PHASE B: dDy = t @ W2t^T (+ fused dy-matvec) ==========
      {
        GLL16(asx + w * 512 + lane * 4,       &asL[w * 512], 1);
        GLL16(asx + w * 512 + 256 + lane * 4, &asL[w * 512 + 256], 1);
        issueB(0, 0); issueB(1, 1); issueB(2, 2);
        f32x4 acc = {0.f,0.f,0.f,0.f};
        float dys = 0.f;
        int cb = 0, ic = 3;
        for (int c = 0; c < 16; ++c) {
          if (c < 13) { issueB(ic, c + 3); ic = (ic == 4) ? 0 : ic + 1; }
          if (c < 13) { WAITV(9); } else if (c == 13) { WAITV(6); }
          else if (c == 14) { WAITV(3); } else { WAITV(0); }
          SBAR();
          const short* tA = tiles + cb * 6144;
          const short* tB = tA + 4096;
#pragma unroll
          for (int kk = 0; kk < 64; kk += 32) {
            int gq = kpar * 8 + (kk >> 3) + quad;      // logical granule 0..15
            int ps = (((gq & 8) | ((gq & 7) ^ l7)) << 3);
            short8 a = *(const short8*)&tA[(msub * 16 + l16) * 128 + ps];
            short8 b = *(const short8*)&tB[l16 * 128 + ps];
            acc = __builtin_amdgcn_mfma_f32_16x16x32_bf16(a, b, acc, 0, 0, 0);
          }
          {
            int pd = (((dseg & 8) | ((dseg & 7) ^ (dcol & 7))) << 3);
            uint4 wq = *(const uint4*)&tB[dcol * 128 + pd];
            dys += dot8(wq, &asL[c * 128 + dseg * 8]);
          }
          cb = (cb == 4) ? 0 : cb + 1;
        }
        if (kpar == 1)
          for (int r = 0; r < 4; ++r) paccL[(msub * 64 + lane) * 4 + r] = acc[r];
        dyp[dseg][dcol] = dys;
        __syncthreads();
        if (kpar == 0) {
          f32x4 o = acc;
          for (int r = 0; r < 4; ++r) o[r] += paccL[(msub * 64 + lane) * 4 + r];
          if (st == 0) K1 = o; else if (st == 1) K2 = o; else if (st == 2) K3 = o;
          if (st < 3) {
            for (int r = 0; r < 4; ++r) {
              float v = DyR[r] + cn * o[r];
              Vbuf[(size_t)(erow0 + r) * DIM + ecol] = f2bfu(v);
            }
          } else {
            const float dt6 = DT / 6.f;
            for (int r = 0; r < 4; ++r) {
              float v = DyR[r] + dt6 * (K1[r] + 2.f * K2[r] + 2.f * K3[r] + o[r]);
              DyR[r] = v;
              Vbuf[(size_t)(erow0 + r) * DIM + ecol] = f2bfu(v);
              if (ss & 1) out[(size_t)(ss / 2 + 1) * ROWSZ + DIM + (size_t)(erow0 + r) * DIM + ecol] = v;
            }
          }
        }
        if (t < 16) {
          float r0 = 0.f;
#pragma unroll
          for (int q2 = 0; q2 < 16; ++q2) r0 += dyp[q2][t];
          float k4 = r0 + b2[nB + t];
          if (st == 0) kd1 = k4; else if (st == 1) kd2 = k4; else if (st == 2) kd3 = k4;
          if (st < 3) {
            ytx[nB + t] = yR + cn * k4;
          } else {
            yR += (DT / 6.f) * (kd1 + 2.f * kd2 + 2.f * kd3 + k4);
            ytx[nB + t] = yR;
            if ((ss & 1) && grp == 0) out[(size_t)(ss / 2 + 1) * ROWSZ + nB + t] = yR;
          }
        }
      }
      xbar(arr, gen, barid++, lead);
    }
  }
}

extern "C" void kernel_launch(void* const* d_in, const int* in_sizes, int n_in,
                              void* d_out, int out_size, void* d_ws, size_t ws_size,
                              hipStream_t stream) {
  const float* y0  = (const float*)d_in[1];
  const float* Dy0 = (const float*)d_in[2];
  const float* W1  = (const float*)d_in[3];
  const float* b1  = (const float*)d_in[4];
  const float* W2  = (const float*)d_in[5];
  const float* b2  = (const float*)d_in[6];
  float* out = (float*)d_out;

  char* p = (char*)d_ws;
  auto alloc = [&](size_t bytes) {
    char* r = p;
    p += (bytes + 255) & ~(size_t)255;
    return r;
  };
  unsigned short* W1t  = (unsigned short*)alloc((size_t)HID * DIM * 2);
  unsigned short* W2t  = (unsigned short*)alloc((size_t)DIM * HID * 2);
  unsigned short* Vbuf = (unsigned short*)alloc((size_t)DIM * DIM * 2);
  unsigned short* tbuf = (unsigned short*)alloc((size_t)DIM * HID * 2);
  float* yts  = (float*)alloc(16 * DIM * 4);
  float* a_ss = (float*)alloc(16 * HID * 4);
  int* ctrl   = (int*)alloc(8192);

  hipMemsetAsync(ctrl, 0, 8192, stream);
  k_transpose_bf16<<<dim3(HID / 32, DIM / 32), 256, 0, stream>>>(W1, (__hip_bfloat16*)W1t, DIM, HID);
  k_transpose_bf16<<<dim3(DIM / 32, HID / 32), 256, 0, stream>>>(W2, (__hip_bfloat16*)W2t, HID, DIM);
  k_persist<<<512, 256, 0, stream>>>(y0, Dy0, W1t, W2t, b1, b2,
                                     Vbuf, tbuf, yts, a_ss, ctrl, out);
}